// Round 8
// baseline (274.412 us; speedup 1.0000x reference)
//
#include <hip/hip_runtime.h>
#include <math.h>

#define N_NODES 100000
#define HID 128
#define NB 782          // ceil(N_NODES / 128) buckets, 128 dst nodes each
#define CAP 4096        // per-bucket capacity in col (mean 2046, +45 sigma)
#define NBLK 256        // bucket-scatter blocks (1 per CU)
#define BTILE 6250      // edges per bucket block (256*6250 = 1.6M)
#define SUBCAP 32       // per-(block,bucket) capacity; lambda=8.0, P(>32)~1e-11
#define SCAP 3072       // per-bucket LDS capacity in k_bfill (+22 sigma)
#define WPB 32          // wprep tail blocks in k_bfill grid (512 thr each)
#define EBLK 3125       // embed blocks in fused bucket+embed kernel (32 nodes each)

typedef __attribute__((ext_vector_type(8))) short bf16x8;
typedef __attribute__((ext_vector_type(4))) float f32x4;
typedef __attribute__((ext_vector_type(2))) float f32x2;

__device__ __forceinline__ unsigned short f2bf(float f) {
  union { float f; unsigned u; } v; v.f = f;
  unsigned r = v.u + 0x7FFFu + ((v.u >> 16) & 1u);  // RNE
  return (unsigned short)(r >> 16);
}
__device__ __forceinline__ unsigned packbf(float lo, float hi) {
  return (unsigned)f2bf(lo) | ((unsigned)f2bf(hi) << 16);
}
__device__ __forceinline__ unsigned pkfp8x4(float a, float b, float c, float d) {
  int v = __builtin_amdgcn_cvt_pk_fp8_f32(a, b, 0, false);
  v = __builtin_amdgcn_cvt_pk_fp8_f32(c, d, v, true);
  return (unsigned)v;
}
__device__ __forceinline__ float bflo(unsigned u) {
  union { unsigned u; float f; } v; v.u = u << 16; return v.f;
}
__device__ __forceinline__ float bfhi(unsigned u) {
  union { unsigned u; float f; } v; v.u = u & 0xFFFF0000u; return v.f;
}
__device__ __forceinline__ void acc_add_fp8(float* a, unsigned w) {
  f32x2 p0 = __builtin_amdgcn_cvt_pk_f32_fp8((int)w, false);
  f32x2 p1 = __builtin_amdgcn_cvt_pk_f32_fp8((int)w, true);
  a[0] += p0.x; a[1] += p0.y; a[2] += p1.x; a[3] += p1.y;
}
__device__ __forceinline__ void acc_add_row(float* a, uint4 u) {
  acc_add_fp8(a + 0, u.x);
  acc_add_fp8(a + 4, u.y);
  acc_add_fp8(a + 8, u.z);
  acc_add_fp8(a + 12, u.w);
}

// ---------------------------------------------------------------------------
// FUSED bucket-scatter + embed (grid-split, 512 threads). ROUND-1 config
// (NBLK=256/SUBCAP=32): NBLK=512 regressed (+4us, r5); global-atomic scatter
// catastrophically regressed (143us: random 4B col writes -> cross-XCD line
// ping-pong, 105MB HBM writes, r6). Keep LDS-sorted two-pass.
// ---------------------------------------------------------------------------
__global__ __launch_bounds__(512) void k_bktembed(
    const int* __restrict__ src, const int* __restrict__ dst,
    int* __restrict__ gcnt, unsigned* __restrict__ bdata2, int E,
    const float* __restrict__ x, const int* __restrict__ uid,
    const int* __restrict__ lid, const float* __restrict__ timef,
    const float* __restrict__ utab, const float* __restrict__ ltab,
    const float* __restrict__ Wt, const float* __restrict__ bt,
    unsigned short* __restrict__ h0, unsigned char* __restrict__ h0f8) {
  __shared__ int hcnt[NB];
  int t = threadIdx.x;
  if (blockIdx.x < NBLK) {
    // ---------------- bucket scatter ----------------
    int blk = blockIdx.x;
    int e0 = blk * BTILE;
    int e1 = min(e0 + BTILE, E);
    for (int i = t; i < NB; i += 512) hcnt[i] = 0;
    __syncthreads();
#pragma unroll 4
    for (int e = e0 + t; e < e1; e += 512) {
      int d = dst[e], s = src[e];
      int b = d >> 7;
      int pos = atomicAdd(&hcnt[b], 1);
      if (pos < SUBCAP)
        bdata2[((size_t)blk * NB + b) * SUBCAP + pos] =
            ((unsigned)s << 7) | (unsigned)(d & 127);
    }
    __syncthreads();
    for (int i = t; i < NB; i += 512)
      gcnt[blk * NB + i] = hcnt[i];  // block-major: private cache lines
    return;
  }
  // ---------------- embed: 32 nodes/block, thread = 8 contiguous feats ----
  int v = (blockIdx.x - NBLK) * 32 + (t >> 4);
  int g = t & 15;  // 8-feature group
  if (v >= N_NODES) return;
  float val[8];
  if (g < 8) {
    const float4* xp = (const float4*)&x[(size_t)v * 64 + g * 8];
    float4 a = xp[0], b = xp[1];
    val[0] = a.x; val[1] = a.y; val[2] = a.z; val[3] = a.w;
    val[4] = b.x; val[5] = b.y; val[6] = b.z; val[7] = b.w;
  } else if (g < 12) {
    const float4* up = (const float4*)&utab[(size_t)uid[v] * 32 + (g - 8) * 8];
    float4 a = up[0], b = up[1];
    val[0] = a.x; val[1] = a.y; val[2] = a.z; val[3] = a.w;
    val[4] = b.x; val[5] = b.y; val[6] = b.z; val[7] = b.w;
  } else if (g < 14) {
    const float4* lp = (const float4*)&ltab[(size_t)lid[v] * 16 + (g - 12) * 8];
    float4 a = lp[0], b = lp[1];
    val[0] = a.x; val[1] = a.y; val[2] = a.z; val[3] = a.w;
    val[4] = b.x; val[5] = b.y; val[6] = b.z; val[7] = b.w;
  } else {
    int c0 = (g - 14) * 8;
    float4 tf = *(const float4*)&timef[(size_t)v * 4];
#pragma unroll
    for (int i = 0; i < 8; ++i) {
      int c = c0 + i;
      val[i] = bt[c] + tf.x * Wt[c] + tf.y * Wt[16 + c] + tf.z * Wt[32 + c] +
               tf.w * Wt[48 + c];
    }
  }
  uint4 ob;
  ob.x = packbf(val[0], val[1]);
  ob.y = packbf(val[2], val[3]);
  ob.z = packbf(val[4], val[5]);
  ob.w = packbf(val[6], val[7]);
  *(uint4*)&h0[(size_t)v * 128 + g * 8] = ob;
  uint2 of;
  of.x = pkfp8x4(val[0], val[1], val[2], val[3]);
  of.y = pkfp8x4(val[4], val[5], val[6], val[7]);
  *(uint2*)&h0f8[(size_t)v * 128 + g * 8] = of;
}

// ---------------------------------------------------------------------------
// Per-bucket gather + counting sort (+ wprep tail blocks), 512 threads.
// ---------------------------------------------------------------------------
__global__ __launch_bounds__(512) void k_bfill(
    const int* __restrict__ gcnt, const unsigned* __restrict__ bdata2,
    int* __restrict__ rstart, int* __restrict__ rdeg, int* __restrict__ col,
    const float* __restrict__ W1l, const float* __restrict__ W1r,
    const float* __restrict__ W2l, const float* __restrict__ W2r,
    unsigned short* __restrict__ WT) {
  int b = blockIdx.x;
  int t = threadIdx.x;
  if (b >= NB) {
    // ---------------- wprep tail: 32 blocks x 512 thr x 4 = 65536 elems ----
    int lin = ((b - NB) * 512 + t) * 4;
    int m = lin >> 14;
    int rem = lin & 16383;
    int f = rem >> 7;
    int k0 = rem & 127;
    const float* W = (m == 0) ? W1l : (m == 1) ? W1r : (m == 2) ? W2l : W2r;
    unsigned short o[4];
#pragma unroll
    for (int j = 0; j < 4; ++j) o[j] = f2bf(W[(size_t)(k0 + j) * 128 + f]);
    uint2 pk;
    pk.x = (unsigned)o[0] | ((unsigned)o[1] << 16);
    pk.y = (unsigned)o[2] | ((unsigned)o[3] << 16);
    *(uint2*)&WT[m * 16384 + f * 128 + k0] = pk;
    return;
  }
  __shared__ unsigned sdata[SCAP];
  __shared__ int soff[NBLK];
  __shared__ int scnt[NBLK];
  __shared__ int wsum[8];
  __shared__ int lcnt[128];
  __shared__ int wtot;
  int lane = t & 63, wv = t >> 6;

  // ---- scan sub-run counts (clamped to SUBCAP) ----
  int c = (t < NBLK) ? min(gcnt[t * NB + b], SUBCAP) : 0;
  int x = c;
#pragma unroll
  for (int off = 1; off < 64; off <<= 1) {
    int v = __shfl_up(x, off);
    if (lane >= off) x += v;
  }
  if (lane == 63) wsum[wv] = x;
  __syncthreads();
  int add = 0;
#pragma unroll
  for (int k = 0; k < 8; ++k)
    if (k < wv) add += wsum[k];
  x += add;
  int tot = 0;
#pragma unroll
  for (int k = 0; k < 4; ++k) tot += wsum[k];  // sub-runs live in waves 0-3
  tot = min(tot, SCAP);
  if (t < NBLK) { soff[t] = x - c; scnt[t] = c; }
  if (t < 128) lcnt[t] = 0;
  __syncthreads();

  // ---- uint4 gather of sub-runs into sdata ----
  for (int i = t; i < NBLK * 8; i += 512) {
    int j = i >> 3, p4 = (i & 7) * 4;
    int cj = scnt[j];
    if (p4 < cj) {
      uint4 v = *(const uint4*)&bdata2[((size_t)j * NB + b) * SUBCAP + p4];
      int bs = soff[j] + p4;
      int n = min(4, cj - p4);
      unsigned vv[4] = {v.x, v.y, v.z, v.w};
#pragma unroll
      for (int e = 0; e < 4; ++e)
        if (e < n && bs + e < SCAP) sdata[bs + e] = vv[e];
    }
  }
  __syncthreads();

  // ---- histogram by dstLow ----
  for (int i = t; i < tot; i += 512) atomicAdd(&lcnt[sdata[i] & 127u], 1);
  __syncthreads();

  int node0 = b * 128;
  int base = b * CAP;
  if (t < 128) {
    int cc = lcnt[t];
    int xx = cc;
#pragma unroll
    for (int off = 1; off < 64; off <<= 1) {
      int v = __shfl_up(xx, off);
      if (lane >= off) xx += v;
    }
    if (t == 63) wtot = xx;
    __syncthreads();
    if (t >= 64) xx += wtot;
    int excl = xx - cc;
    if (node0 + t < N_NODES) {
      rstart[node0 + t] = base + excl;
      rdeg[node0 + t] = cc;
    }
    lcnt[t] = excl;  // scatter cursor
  } else {
    __syncthreads();
  }
  __syncthreads();
  for (int i = t; i < tot; i += 512) {
    unsigned v = sdata[i];
    int pos = base + atomicAdd(&lcnt[v & 127u], 1);
    col[pos] = (int)(v >> 7);
  }
}

// ---------------------------------------------------------------------------
// FUSED mean-aggregation + dual GEMM, 32-NODE tiles, 256 threads (3125
// blocks). Same phase structure as the 58.6us 64-node anchor; tile halved so
// LDS drops 34.8KB -> 17.4KB => 8 blocks/CU (32 wave-slots, was 16) for the
// latency-bound gather, and the 12.2-blocks/CU grid smooths stragglers.
// Gather is one static pass: 32 groups x 8 lanes, one node each (dynamic
// pool removed — r7 showed it null-to-negative). Hs stays LDS-staged (global
// reads in the MFMA loop cost +11us, r4). Do NOT cap VGPR below 128 (spill,
// r2/r3).
// ---------------------------------------------------------------------------
template <bool CLS>
__global__ __launch_bounds__(256, 4) void k_aggemm(
    const unsigned char* __restrict__ hf8, const int* __restrict__ rstart,
    const int* __restrict__ rdeg, const int* __restrict__ col,
    const unsigned short* __restrict__ hin,
    const unsigned short* __restrict__ WlT, const unsigned short* __restrict__ WrT,
    const float* __restrict__ bias, unsigned short* __restrict__ hout,
    unsigned char* __restrict__ houtf8,
    const float* __restrict__ Wc, const float* __restrict__ bc,
    float* __restrict__ out) {
  __shared__ unsigned short SB[2 * 32 * 136];  // As | Hs (17.4KB); Ot aliases As
  unsigned short* As = SB;
  unsigned short* Hs = SB + 32 * 136;
  unsigned short* Ot = SB;
  float* zred = (float*)SB;  // CLS: 4*32 floats
  int t = threadIdx.x;
  int lane = t & 63;
  int wave = t >> 6;
  int wn = wave * 32;        // feat strip
  int l15 = lane & 15;
  int quad = lane >> 4;
  int mbase = blockIdx.x * 32;

  int r = t >> 3, q = t & 7;  // node-row (0..31), 16B segment (0..7)

  // ---- issue hin row loads early (written to LDS after gather) ----
  uint4 hv[2];  // 32B of the 256B bf16 row
  {
    int gn = mbase + r;
    if (gn < N_NODES) {
      const uint4* hp = (const uint4*)(hin + (size_t)gn * 128 + q * 16);
      hv[0] = hp[0]; hv[1] = hp[1];
    } else {
      hv[0] = make_uint4(0, 0, 0, 0); hv[1] = make_uint4(0, 0, 0, 0);
    }
  }

  // ---- gather-mean into As: 32 nodes, 8 lanes/node, single static pass ----
  {
    const uint4* h8 = (const uint4*)hf8;  // 8 uint4 per 128B fp8 row
    int v = mbase + r;
    float acc[16];
#pragma unroll
    for (int i = 0; i < 16; ++i) acc[i] = 0.f;
    float inv = 0.f;
    if (v < N_NODES) {
      int s0 = rstart[v];
      int deg = rdeg[v];
      int s1 = s0 + deg;
      int j = s0;
      for (; j + 4 <= s1; j += 4) {
        uint4 r0 = h8[(size_t)col[j] * 8 + q];
        uint4 r1 = h8[(size_t)col[j + 1] * 8 + q];
        uint4 r2 = h8[(size_t)col[j + 2] * 8 + q];
        uint4 r3 = h8[(size_t)col[j + 3] * 8 + q];
        acc_add_row(acc, r0);
        acc_add_row(acc, r1);
        acc_add_row(acc, r2);
        acc_add_row(acc, r3);
      }
      for (; j < s1; ++j) acc_add_row(acc, h8[(size_t)col[j] * 8 + q]);
      inv = 1.f / (float)(deg > 0 ? deg : 1);
    }
    uint4 o0, o1;
    o0.x = packbf(acc[0] * inv, acc[1] * inv);
    o0.y = packbf(acc[2] * inv, acc[3] * inv);
    o0.z = packbf(acc[4] * inv, acc[5] * inv);
    o0.w = packbf(acc[6] * inv, acc[7] * inv);
    o1.x = packbf(acc[8] * inv, acc[9] * inv);
    o1.y = packbf(acc[10] * inv, acc[11] * inv);
    o1.z = packbf(acc[12] * inv, acc[13] * inv);
    o1.w = packbf(acc[14] * inv, acc[15] * inv);
    *(uint4*)&As[r * 136 + q * 16] = o0;
    *(uint4*)&As[r * 136 + q * 16 + 8] = o1;
  }

  // ---- late LDS-write of staged hin rows ----
  *(uint4*)&Hs[r * 136 + q * 16] = hv[0];
  *(uint4*)&Hs[r * 136 + q * 16 + 8] = hv[1];
  __syncthreads();

  f32x4 acc4[2][2];
#pragma unroll
  for (int i = 0; i < 2; ++i)
#pragma unroll
    for (int j = 0; j < 2; ++j) acc4[i][j] = (f32x4){0.f, 0.f, 0.f, 0.f};

#pragma unroll
  for (int ks = 0; ks < 4; ++ks) {
    int kb = ks * 32 + quad * 8;
    bf16x8 bL[2], bR[2];
#pragma unroll
    for (int jn = 0; jn < 2; ++jn) {
      int f = wn + jn * 16 + l15;
      bL[jn] = *(const bf16x8*)&WlT[(size_t)f * 128 + kb];
      bR[jn] = *(const bf16x8*)&WrT[(size_t)f * 128 + kb];
    }
    bf16x8 aA[2], aH[2];
#pragma unroll
    for (int im = 0; im < 2; ++im) {
      aA[im] = *(const bf16x8*)&As[(im * 16 + l15) * 136 + kb];
      aH[im] = *(const bf16x8*)&Hs[(im * 16 + l15) * 136 + kb];
    }
#pragma unroll
    for (int im = 0; im < 2; ++im)
#pragma unroll
      for (int jn = 0; jn < 2; ++jn)
        acc4[im][jn] = __builtin_amdgcn_mfma_f32_16x16x32_bf16(
            aA[im], bL[jn], acc4[im][jn], 0, 0, 0);
#pragma unroll
    for (int im = 0; im < 2; ++im)
#pragma unroll
      for (int jn = 0; jn < 2; ++jn)
        acc4[im][jn] = __builtin_amdgcn_mfma_f32_16x16x32_bf16(
            aH[im], bR[jn], acc4[im][jn], 0, 0, 0);
  }

  float bv[2];
#pragma unroll
  for (int jn = 0; jn < 2; ++jn) bv[jn] = bias[wn + jn * 16 + l15];

  __syncthreads();  // As/Hs dead; Ot/zred alias

  if (!CLS) {
#pragma unroll
    for (int im = 0; im < 2; ++im)
#pragma unroll
      for (int rr = 0; rr < 4; ++rr) {
        int rloc = im * 16 + quad * 4 + rr;
#pragma unroll
        for (int jn = 0; jn < 2; ++jn)
          Ot[rloc * 136 + wn + jn * 16 + l15] =
              f2bf(fmaxf(acc4[im][jn][rr] + bv[jn], 0.f));
      }
    __syncthreads();
    int node = mbase + r;
    if (node < N_NODES) {
      uint4 d0[2];
      const uint4* srcp = (const uint4*)&Ot[r * 136 + q * 16];
      uint4* dstp = (uint4*)&hout[(size_t)node * 128 + q * 16];
      d0[0] = srcp[0]; d0[1] = srcp[1];
      dstp[0] = d0[0]; dstp[1] = d0[1];
      // fp8 copy: 16 values -> 16 bytes
      unsigned w[4];
#pragma unroll
      for (int i = 0; i < 2; ++i) {
        unsigned u[4] = {d0[i].x, d0[i].y, d0[i].z, d0[i].w};
#pragma unroll
        for (int p = 0; p < 2; ++p) {
          w[i * 2 + p] = pkfp8x4(bflo(u[p * 2]), bfhi(u[p * 2]),
                                 bflo(u[p * 2 + 1]), bfhi(u[p * 2 + 1]));
        }
      }
      *(uint4*)&houtf8[(size_t)node * 128 + q * 16] =
          make_uint4(w[0], w[1], w[2], w[3]);
    }
  } else {
    float wcv[2];
#pragma unroll
    for (int jn = 0; jn < 2; ++jn) wcv[jn] = Wc[wn + jn * 16 + l15];
#pragma unroll
    for (int im = 0; im < 2; ++im) {
#pragma unroll
      for (int rr = 0; rr < 4; ++rr) {
        float p = 0.f;
#pragma unroll
        for (int jn = 0; jn < 2; ++jn)
          p += fmaxf(acc4[im][jn][rr] + bv[jn], 0.f) * wcv[jn];
        p += __shfl_xor(p, 1);
        p += __shfl_xor(p, 2);
        p += __shfl_xor(p, 4);
        p += __shfl_xor(p, 8);
        if (l15 == 0) zred[wave * 32 + im * 16 + quad * 4 + rr] = p;
      }
    }
    __syncthreads();
    if (t < 32) {
      int node = mbase + t;
      if (node < N_NODES) {
        float z = zred[t] + zred[32 + t] + zred[64 + t] + zred[96 + t] + bc[0];
        out[node] = 1.f / (1.f + expf(-z));
      }
    }
  }
}

// ---------------------------------------------------------------------------
extern "C" void kernel_launch(void* const* d_in, const int* in_sizes, int n_in,
                              void* d_out, int out_size, void* d_ws, size_t ws_size,
                              hipStream_t stream) {
  const float* x     = (const float*)d_in[0];
  const int*   eidx  = (const int*)d_in[1];
  const int*   uid   = (const int*)d_in[2];
  const int*   lid   = (const int*)d_in[3];
  const float* timef = (const float*)d_in[4];
  const float* utab  = (const float*)d_in[5];
  const float* ltab  = (const float*)d_in[6];
  const float* Wt    = (const float*)d_in[7];
  const float* bt    = (const float*)d_in[8];
  const float* W1l   = (const float*)d_in[9];
  const float* b1    = (const float*)d_in[10];
  const float* W1r   = (const float*)d_in[11];
  const float* W2l   = (const float*)d_in[12];
  const float* b2    = (const float*)d_in[13];
  const float* W2r   = (const float*)d_in[14];
  const float* Wc    = (const float*)d_in[15];
  const float* bc    = (const float*)d_in[16];
  float* out = (float*)d_out;

  const int E = in_sizes[1] / 2;
  const int* src = eidx;
  const int* dst = eidx + E;

  char* ws = (char*)d_ws;
  size_t off = 0;
  auto alloc = [&](size_t bytes) -> void* {
    void* p = ws + off;
    off += (bytes + 255) & ~(size_t)255;
    return p;
  };
  const size_t HBYTES = (size_t)N_NODES * 128 * sizeof(unsigned short);  // 25.6MB
  const size_t FBYTES = (size_t)N_NODES * 128;                           // 12.8MB
  unsigned short* h0  = (unsigned short*)alloc(HBYTES);
  unsigned short* h1  = (unsigned short*)alloc(HBYTES);
  unsigned char* h0f8 = (unsigned char*)alloc(FBYTES);
  unsigned char* h1f8 = (unsigned char*)alloc(FBYTES);
  unsigned short* WT  = (unsigned short*)alloc(4 * 16384 * sizeof(unsigned short));
  unsigned* bdata2    = (unsigned*)alloc((size_t)NBLK * NB * SUBCAP * 4);  // 25.6MB
  int* gcnt           = (int*)alloc((size_t)NBLK * NB * 4);                // 800KB
  int* col            = (int*)alloc((size_t)NB * CAP * 4);                 // 12.8MB
  int* rstart         = (int*)alloc((size_t)N_NODES * 4);
  int* rdeg           = (int*)alloc((size_t)N_NODES * 4);
  (void)ws_size; (void)n_in; (void)out_size;

  // ---- fused bucket scatter (latency-bound) + embed (BW-bound) ----
  k_bktembed<<<NBLK + EBLK, 512, 0, stream>>>(src, dst, gcnt, bdata2, E,
                                              x, uid, lid, timef, utab, ltab,
                                              Wt, bt, h0, h0f8);
  // ---- CSR finalize + wprep tail ----
  k_bfill<<<NB + WPB, 512, 0, stream>>>(gcnt, bdata2, rstart, rdeg, col,
                                        W1l, W1r, W2l, W2r, WT);

  // ---- layer 1: fused gather-mean + dual GEMM (32-node tiles) ----
  k_aggemm<false><<<(N_NODES + 31) / 32, 256, 0, stream>>>(
      h0f8, rstart, rdeg, col, h0, WT, WT + 16384, b1, h1, h1f8,
      nullptr, nullptr, nullptr);

  // ---- layer 2: fused gather-mean + dual GEMM + classifier ----
  k_aggemm<true><<<(N_NODES + 31) / 32, 256, 0, stream>>>(
      h1f8, rstart, rdeg, col, h1, WT + 32768, WT + 49152, b2,
      nullptr, nullptr, Wc, bc, out);
}

// Round 9
// 248.797 us; speedup vs baseline: 1.1030x; 1.1030x over previous
//
#include <hip/hip_runtime.h>
#include <math.h>

#define N_NODES 100000
#define HID 128
#define NB 782          // ceil(N_NODES / 128) buckets, 128 dst nodes each
#define CAP 4096        // per-bucket capacity in col (mean 2046, +45 sigma)
#define NBLK 256        // bucket-scatter blocks (1 per CU)
#define BTILE 6250      // edges per bucket block (256*6250 = 1.6M)
#define BREG 6272       // dense bdata2 region per block (64B-aligned)
#define SUBCAP 32       // bfill per-sub-run read clamp (lambda=8, P(>32)~1e-11)
#define SCAP 3072       // per-bucket LDS capacity in k_bfill (+22 sigma)
#define WPB 32          // wprep tail blocks in k_bfill grid (512 thr each)
#define EBLK 3125       // embed blocks in fused bucket+embed kernel (32 nodes each)

typedef __attribute__((ext_vector_type(8))) short bf16x8;
typedef __attribute__((ext_vector_type(4))) float f32x4;
typedef __attribute__((ext_vector_type(2))) float f32x2;

__device__ __forceinline__ unsigned short f2bf(float f) {
  union { float f; unsigned u; } v; v.f = f;
  unsigned r = v.u + 0x7FFFu + ((v.u >> 16) & 1u);  // RNE
  return (unsigned short)(r >> 16);
}
__device__ __forceinline__ unsigned packbf(float lo, float hi) {
  return (unsigned)f2bf(lo) | ((unsigned)f2bf(hi) << 16);
}
__device__ __forceinline__ unsigned pkfp8x4(float a, float b, float c, float d) {
  int v = __builtin_amdgcn_cvt_pk_fp8_f32(a, b, 0, false);
  v = __builtin_amdgcn_cvt_pk_fp8_f32(c, d, v, true);
  return (unsigned)v;
}
__device__ __forceinline__ float bflo(unsigned u) {
  union { unsigned u; float f; } v; v.u = u << 16; return v.f;
}
__device__ __forceinline__ float bfhi(unsigned u) {
  union { unsigned u; float f; } v; v.u = u & 0xFFFF0000u; return v.f;
}
__device__ __forceinline__ void acc_add_fp8(float* a, unsigned w) {
  f32x2 p0 = __builtin_amdgcn_cvt_pk_f32_fp8((int)w, false);
  f32x2 p1 = __builtin_amdgcn_cvt_pk_f32_fp8((int)w, true);
  a[0] += p0.x; a[1] += p0.y; a[2] += p1.x; a[3] += p1.y;
}
__device__ __forceinline__ void acc_add_row(float* a, uint4 u) {
  acc_add_fp8(a + 0, u.x);
  acc_add_fp8(a + 4, u.y);
  acc_add_fp8(a + 8, u.z);
  acc_add_fp8(a + 12, u.w);
}

// ---------------------------------------------------------------------------
// FUSED bucket-scatter + embed (grid-split, 512 threads).
// Bucket blocks now LDS-BIN their edge tile: histogram -> scan -> LDS
// scatter -> CONTIGUOUS dump of the dense bucket-sorted bin (4 lines/wave
// instead of 64 scattered lines/wave — the old scattered 4B stores were the
// ~50us cost; r6's global-atomic variant proved random 4B stores are fatal).
// bdata2 is now dense per-block regions; goff[] records per-bucket offsets.
// ---------------------------------------------------------------------------
__global__ __launch_bounds__(512) void k_bktembed(
    const int* __restrict__ src, const int* __restrict__ dst,
    int* __restrict__ gcnt, int* __restrict__ goff,
    unsigned* __restrict__ bdata2, int E,
    const float* __restrict__ x, const int* __restrict__ uid,
    const int* __restrict__ lid, const float* __restrict__ timef,
    const float* __restrict__ utab, const float* __restrict__ ltab,
    const float* __restrict__ Wt, const float* __restrict__ bt,
    unsigned short* __restrict__ h0, unsigned char* __restrict__ h0f8) {
  __shared__ unsigned sbin[BREG];  // 25.1KB dense bin
  __shared__ int bcnt[NB];
  __shared__ int boff[NB];
  __shared__ int bws[8];
  int t = threadIdx.x;
  if (blockIdx.x < NBLK) {
    // ---------------- LDS-binned bucket scatter ----------------
    int blk = blockIdx.x;
    int e0 = blk * BTILE;
    int e1 = min(e0 + BTILE, E);
    for (int i = t; i < NB; i += 512) bcnt[i] = 0;
    __syncthreads();
    // pass A: histogram
    for (int e = e0 + t; e < e1; e += 512) atomicAdd(&bcnt[dst[e] >> 7], 1);
    __syncthreads();
    // ordered scan over NB buckets, 2 consecutive buckets per thread
    int lane = t & 63, wv = t >> 6;
    int b0 = t * 2, b1 = t * 2 + 1;
    int ca = (b0 < NB) ? bcnt[b0] : 0;
    int cb = (b1 < NB) ? bcnt[b1] : 0;
    int s = ca + cb;
    int xx = s;
#pragma unroll
    for (int off = 1; off < 64; off <<= 1) {
      int v = __shfl_up(xx, off);
      if (lane >= off) xx += v;
    }
    if (lane == 63) bws[wv] = xx;
    __syncthreads();
    int add = 0;
#pragma unroll
    for (int k = 0; k < 8; ++k)
      if (k < wv) add += bws[k];
    xx += add;
    int excl = xx - s;
    if (b0 < NB) boff[b0] = excl;
    if (b1 < NB) boff[b1] = excl + ca;
    __syncthreads();
    // persist exact counts + dense offsets (contiguous writes)
    for (int i = t; i < NB; i += 512) {
      gcnt[blk * NB + i] = bcnt[i];
      goff[blk * NB + i] = boff[i];
    }
    __syncthreads();  // goff reads done before boff becomes a cursor
    // pass B: LDS scatter (boff = cursor); tile re-read is L2-hot
    for (int e = e0 + t; e < e1; e += 512) {
      int d = dst[e], sv = src[e];
      int p = atomicAdd(&boff[d >> 7], 1);
      sbin[p] = ((unsigned)sv << 7) | (unsigned)(d & 127);
    }
    __syncthreads();
    // contiguous dump: 64 consecutive lanes -> 4 full lines per wave
    int tot = e1 - e0;
    for (int i = t; i < tot; i += 512)
      bdata2[(size_t)blk * BREG + i] = sbin[i];
    return;
  }
  // ---------------- embed: 32 nodes/block, thread = 8 contiguous feats ----
  int v = (blockIdx.x - NBLK) * 32 + (t >> 4);
  int g = t & 15;  // 8-feature group
  if (v >= N_NODES) return;
  float val[8];
  if (g < 8) {
    const float4* xp = (const float4*)&x[(size_t)v * 64 + g * 8];
    float4 a = xp[0], b = xp[1];
    val[0] = a.x; val[1] = a.y; val[2] = a.z; val[3] = a.w;
    val[4] = b.x; val[5] = b.y; val[6] = b.z; val[7] = b.w;
  } else if (g < 12) {
    const float4* up = (const float4*)&utab[(size_t)uid[v] * 32 + (g - 8) * 8];
    float4 a = up[0], b = up[1];
    val[0] = a.x; val[1] = a.y; val[2] = a.z; val[3] = a.w;
    val[4] = b.x; val[5] = b.y; val[6] = b.z; val[7] = b.w;
  } else if (g < 14) {
    const float4* lp = (const float4*)&ltab[(size_t)lid[v] * 16 + (g - 12) * 8];
    float4 a = lp[0], b = lp[1];
    val[0] = a.x; val[1] = a.y; val[2] = a.z; val[3] = a.w;
    val[4] = b.x; val[5] = b.y; val[6] = b.z; val[7] = b.w;
  } else {
    int c0 = (g - 14) * 8;
    float4 tf = *(const float4*)&timef[(size_t)v * 4];
#pragma unroll
    for (int i = 0; i < 8; ++i) {
      int c = c0 + i;
      val[i] = bt[c] + tf.x * Wt[c] + tf.y * Wt[16 + c] + tf.z * Wt[32 + c] +
               tf.w * Wt[48 + c];
    }
  }
  uint4 ob;
  ob.x = packbf(val[0], val[1]);
  ob.y = packbf(val[2], val[3]);
  ob.z = packbf(val[4], val[5]);
  ob.w = packbf(val[6], val[7]);
  *(uint4*)&h0[(size_t)v * 128 + g * 8] = ob;
  uint2 of;
  of.x = pkfp8x4(val[0], val[1], val[2], val[3]);
  of.y = pkfp8x4(val[4], val[5], val[6], val[7]);
  *(uint2*)&h0f8[(size_t)v * 128 + g * 8] = of;
}

// ---------------------------------------------------------------------------
// Per-bucket gather + counting sort (+ wprep tail blocks), 512 threads.
// Sub-runs now read from DENSE per-block regions via goff (4 consecutive
// u32 per thread, lane-consecutive -> coalesced).
// ---------------------------------------------------------------------------
__global__ __launch_bounds__(512) void k_bfill(
    const int* __restrict__ gcnt, const int* __restrict__ goff,
    const unsigned* __restrict__ bdata2,
    int* __restrict__ rstart, int* __restrict__ rdeg, int* __restrict__ col,
    const float* __restrict__ W1l, const float* __restrict__ W1r,
    const float* __restrict__ W2l, const float* __restrict__ W2r,
    unsigned short* __restrict__ WT) {
  int b = blockIdx.x;
  int t = threadIdx.x;
  if (b >= NB) {
    // ---------------- wprep tail: 32 blocks x 512 thr x 4 = 65536 elems ----
    int lin = ((b - NB) * 512 + t) * 4;
    int m = lin >> 14;
    int rem = lin & 16383;
    int f = rem >> 7;
    int k0 = rem & 127;
    const float* W = (m == 0) ? W1l : (m == 1) ? W1r : (m == 2) ? W2l : W2r;
    unsigned short o[4];
#pragma unroll
    for (int j = 0; j < 4; ++j) o[j] = f2bf(W[(size_t)(k0 + j) * 128 + f]);
    uint2 pk;
    pk.x = (unsigned)o[0] | ((unsigned)o[1] << 16);
    pk.y = (unsigned)o[2] | ((unsigned)o[3] << 16);
    *(uint2*)&WT[m * 16384 + f * 128 + k0] = pk;
    return;
  }
  __shared__ unsigned sdata[SCAP];
  __shared__ int soff[NBLK];
  __shared__ int scnt[NBLK];
  __shared__ int sgoff[NBLK];
  __shared__ int wsum[8];
  __shared__ int lcnt[128];
  __shared__ int wtot;
  int lane = t & 63, wv = t >> 6;

  // ---- scan sub-run counts (clamped to SUBCAP for the LDS stage) ----
  int c = (t < NBLK) ? min(gcnt[t * NB + b], SUBCAP) : 0;
  int x = c;
#pragma unroll
  for (int off = 1; off < 64; off <<= 1) {
    int v = __shfl_up(x, off);
    if (lane >= off) x += v;
  }
  if (lane == 63) wsum[wv] = x;
  __syncthreads();
  int add = 0;
#pragma unroll
  for (int k = 0; k < 8; ++k)
    if (k < wv) add += wsum[k];
  x += add;
  int tot = 0;
#pragma unroll
  for (int k = 0; k < 4; ++k) tot += wsum[k];  // sub-runs live in waves 0-3
  tot = min(tot, SCAP);
  if (t < NBLK) {
    soff[t] = x - c;
    scnt[t] = c;
    sgoff[t] = goff[t * NB + b];
  }
  if (t < 128) lcnt[t] = 0;
  __syncthreads();

  // ---- gather sub-runs from dense regions into sdata ----
  for (int i = t; i < NBLK * 8; i += 512) {
    int j = i >> 3, p4 = (i & 7) * 4;
    int cj = scnt[j];
    if (p4 < cj) {
      const unsigned* bp = &bdata2[(size_t)j * BREG + sgoff[j] + p4];
      int bs = soff[j] + p4;
      int n = min(4, cj - p4);
#pragma unroll
      for (int e = 0; e < 4; ++e)
        if (e < n && bs + e < SCAP) sdata[bs + e] = bp[e];
    }
  }
  __syncthreads();

  // ---- histogram by dstLow ----
  for (int i = t; i < tot; i += 512) atomicAdd(&lcnt[sdata[i] & 127u], 1);
  __syncthreads();

  int node0 = b * 128;
  int base = b * CAP;
  if (t < 128) {
    int cc = lcnt[t];
    int xx = cc;
#pragma unroll
    for (int off = 1; off < 64; off <<= 1) {
      int v = __shfl_up(xx, off);
      if (lane >= off) xx += v;
    }
    if (t == 63) wtot = xx;
    __syncthreads();
    if (t >= 64) xx += wtot;
    int excl = xx - cc;
    if (node0 + t < N_NODES) {
      rstart[node0 + t] = base + excl;
      rdeg[node0 + t] = cc;
    }
    lcnt[t] = excl;  // scatter cursor
  } else {
    __syncthreads();
  }
  __syncthreads();
  for (int i = t; i < tot; i += 512) {
    unsigned v = sdata[i];
    int pos = base + atomicAdd(&lcnt[v & 127u], 1);
    col[pos] = (int)(v >> 7);
  }
}

// ---------------------------------------------------------------------------
// FUSED mean-aggregation + dual GEMM, 64-node tiles, 256 threads — EXACT
// static anchor (58.8us, VGPR 56, no spill; measured r1/r5). CLOSED lines of
// attack: VGPR cap <128 spills ~220MB (r2/r3); global Hs reads in MFMA loop
// +11us (r4); dynamic node pool -1.2us (r7); 32-node tile +6us (r8);
// occupancy is NOT the limiter — gather sits at the random-128B L2/L3
// service floor.
// ---------------------------------------------------------------------------
template <bool CLS>
__global__ __launch_bounds__(256, 4) void k_aggemm(
    const unsigned char* __restrict__ hf8, const int* __restrict__ rstart,
    const int* __restrict__ rdeg, const int* __restrict__ col,
    const unsigned short* __restrict__ hin,
    const unsigned short* __restrict__ WlT, const unsigned short* __restrict__ WrT,
    const float* __restrict__ bias, unsigned short* __restrict__ hout,
    unsigned char* __restrict__ houtf8,
    const float* __restrict__ Wc, const float* __restrict__ bc,
    float* __restrict__ out) {
  __shared__ unsigned short SB[2 * 64 * 136];  // As | Hs (34.8KB); Ot aliases As
  unsigned short* As = SB;
  unsigned short* Hs = SB + 64 * 136;
  unsigned short* Ot = SB;
  float* zred = (float*)SB;  // CLS: 4*64 floats
  int t = threadIdx.x;
  int lane = t & 63;
  int wave = t >> 6;
  int wn = wave * 32;        // feat strip
  int l15 = lane & 15;
  int quad = lane >> 4;
  int mbase = blockIdx.x * 64;

  // ---- issue hin row loads early (written to LDS after gather) ----
  int sr = t >> 2, sseg = t & 3;  // 4 threads/row, 64B each
  uint4 hv[4];
  {
    int gn = mbase + sr;
    if (gn < N_NODES) {
      const uint4* hp = (const uint4*)(hin + (size_t)gn * 128 + sseg * 32);
#pragma unroll
      for (int i = 0; i < 4; ++i) hv[i] = hp[i];
    } else {
#pragma unroll
      for (int i = 0; i < 4; ++i) hv[i] = make_uint4(0, 0, 0, 0);
    }
  }

  // ---- gather-mean into As: two 32-node half-tiles, 8 lanes/node ----
  const uint4* h8 = (const uint4*)hf8;  // 8 uint4 per 128B fp8 row
#pragma unroll
  for (int half = 0; half < 2; ++half) {
    int r = half * 32 + (t >> 3);
    int q = t & 7;
    int v = mbase + r;
    float acc[16];
#pragma unroll
    for (int i = 0; i < 16; ++i) acc[i] = 0.f;
    float inv = 0.f;
    if (v < N_NODES) {
      int s0 = rstart[v];
      int deg = rdeg[v];
      int s1 = s0 + deg;
      int j = s0;
      for (; j + 4 <= s1; j += 4) {
        uint4 r0 = h8[(size_t)col[j] * 8 + q];
        uint4 r1 = h8[(size_t)col[j + 1] * 8 + q];
        uint4 r2 = h8[(size_t)col[j + 2] * 8 + q];
        uint4 r3 = h8[(size_t)col[j + 3] * 8 + q];
        acc_add_row(acc, r0);
        acc_add_row(acc, r1);
        acc_add_row(acc, r2);
        acc_add_row(acc, r3);
      }
      for (; j < s1; ++j) acc_add_row(acc, h8[(size_t)col[j] * 8 + q]);
      inv = 1.f / (float)(deg > 0 ? deg : 1);
    }
    uint4 o0, o1;
    o0.x = packbf(acc[0] * inv, acc[1] * inv);
    o0.y = packbf(acc[2] * inv, acc[3] * inv);
    o0.z = packbf(acc[4] * inv, acc[5] * inv);
    o0.w = packbf(acc[6] * inv, acc[7] * inv);
    o1.x = packbf(acc[8] * inv, acc[9] * inv);
    o1.y = packbf(acc[10] * inv, acc[11] * inv);
    o1.z = packbf(acc[12] * inv, acc[13] * inv);
    o1.w = packbf(acc[14] * inv, acc[15] * inv);
    *(uint4*)&As[r * 136 + q * 16] = o0;
    *(uint4*)&As[r * 136 + q * 16 + 8] = o1;
  }

  // ---- late LDS-write of staged hin rows ----
#pragma unroll
  for (int i = 0; i < 4; ++i)
    *(uint4*)&Hs[sr * 136 + sseg * 32 + i * 8] = hv[i];
  __syncthreads();

  f32x4 acc4[4][2];
#pragma unroll
  for (int i = 0; i < 4; ++i)
#pragma unroll
    for (int j = 0; j < 2; ++j) acc4[i][j] = (f32x4){0.f, 0.f, 0.f, 0.f};

#pragma unroll
  for (int ks = 0; ks < 4; ++ks) {
    int kb = ks * 32 + quad * 8;
    bf16x8 bL[2], bR[2];
#pragma unroll
    for (int jn = 0; jn < 2; ++jn) {
      int f = wn + jn * 16 + l15;
      bL[jn] = *(const bf16x8*)&WlT[(size_t)f * 128 + kb];
      bR[jn] = *(const bf16x8*)&WrT[(size_t)f * 128 + kb];
    }
    bf16x8 aA[4], aH[4];
#pragma unroll
    for (int im = 0; im < 4; ++im) {
      aA[im] = *(const bf16x8*)&As[(im * 16 + l15) * 136 + kb];
      aH[im] = *(const bf16x8*)&Hs[(im * 16 + l15) * 136 + kb];
    }
#pragma unroll
    for (int im = 0; im < 4; ++im)
#pragma unroll
      for (int jn = 0; jn < 2; ++jn)
        acc4[im][jn] = __builtin_amdgcn_mfma_f32_16x16x32_bf16(
            aA[im], bL[jn], acc4[im][jn], 0, 0, 0);
#pragma unroll
    for (int im = 0; im < 4; ++im)
#pragma unroll
      for (int jn = 0; jn < 2; ++jn)
        acc4[im][jn] = __builtin_amdgcn_mfma_f32_16x16x32_bf16(
            aH[im], bR[jn], acc4[im][jn], 0, 0, 0);
  }

  float bv[2];
#pragma unroll
  for (int jn = 0; jn < 2; ++jn) bv[jn] = bias[wn + jn * 16 + l15];

  __syncthreads();  // As/Hs dead; Ot/zred alias

  if (!CLS) {
#pragma unroll
    for (int im = 0; im < 4; ++im)
#pragma unroll
      for (int rr = 0; rr < 4; ++rr) {
        int rloc = im * 16 + quad * 4 + rr;
#pragma unroll
        for (int jn = 0; jn < 2; ++jn)
          Ot[rloc * 136 + wn + jn * 16 + l15] =
              f2bf(fmaxf(acc4[im][jn][rr] + bv[jn], 0.f));
      }
    __syncthreads();
    int r = t >> 2, seg = t & 3;
    int node = mbase + r;
    if (node < N_NODES) {
      uint4 d0[4];
      const uint4* srcp = (const uint4*)&Ot[r * 136 + seg * 32];
      uint4* dstp = (uint4*)&hout[(size_t)node * 128 + seg * 32];
#pragma unroll
      for (int i = 0; i < 4; ++i) { d0[i] = srcp[i]; dstp[i] = d0[i]; }
      // fp8 copy: 32 values -> 32 bytes
      unsigned w[8];
#pragma unroll
      for (int i = 0; i < 4; ++i) {
        unsigned u[4] = {d0[i].x, d0[i].y, d0[i].z, d0[i].w};
#pragma unroll
        for (int p = 0; p < 2; ++p) {
          w[i * 2 + p] = pkfp8x4(bflo(u[p * 2]), bfhi(u[p * 2]),
                                 bflo(u[p * 2 + 1]), bfhi(u[p * 2 + 1]));
        }
      }
      uint4* fp = (uint4*)&houtf8[(size_t)node * 128 + seg * 32];
      fp[0] = make_uint4(w[0], w[1], w[2], w[3]);
      fp[1] = make_uint4(w[4], w[5], w[6], w[7]);
    }
  } else {
    float wcv[2];
#pragma unroll
    for (int jn = 0; jn < 2; ++jn) wcv[jn] = Wc[wn + jn * 16 + l15];
#pragma unroll
    for (int im = 0; im < 4; ++im) {
#pragma unroll
      for (int rr = 0; rr < 4; ++rr) {
        float p = 0.f;
#pragma unroll
        for (int jn = 0; jn < 2; ++jn)
          p += fmaxf(acc4[im][jn][rr] + bv[jn], 0.f) * wcv[jn];
        p += __shfl_xor(p, 1);
        p += __shfl_xor(p, 2);
        p += __shfl_xor(p, 4);
        p += __shfl_xor(p, 8);
        if (l15 == 0) zred[wave * 64 + im * 16 + quad * 4 + rr] = p;
      }
    }
    __syncthreads();
    if (t < 64) {
      int node = mbase + t;
      if (node < N_NODES) {
        float z = zred[t] + zred[64 + t] + zred[128 + t] + zred[192 + t] + bc[0];
        out[node] = 1.f / (1.f + expf(-z));
      }
    }
  }
}

// ---------------------------------------------------------------------------
extern "C" void kernel_launch(void* const* d_in, const int* in_sizes, int n_in,
                              void* d_out, int out_size, void* d_ws, size_t ws_size,
                              hipStream_t stream) {
  const float* x     = (const float*)d_in[0];
  const int*   eidx  = (const int*)d_in[1];
  const int*   uid   = (const int*)d_in[2];
  const int*   lid   = (const int*)d_in[3];
  const float* timef = (const float*)d_in[4];
  const float* utab  = (const float*)d_in[5];
  const float* ltab  = (const float*)d_in[6];
  const float* Wt    = (const float*)d_in[7];
  const float* bt    = (const float*)d_in[8];
  const float* W1l   = (const float*)d_in[9];
  const float* b1    = (const float*)d_in[10];
  const float* W1r   = (const float*)d_in[11];
  const float* W2l   = (const float*)d_in[12];
  const float* b2    = (const float*)d_in[13];
  const float* W2r   = (const float*)d_in[14];
  const float* Wc    = (const float*)d_in[15];
  const float* bc    = (const float*)d_in[16];
  float* out = (float*)d_out;

  const int E = in_sizes[1] / 2;
  const int* src = eidx;
  const int* dst = eidx + E;

  char* ws = (char*)d_ws;
  size_t off = 0;
  auto alloc = [&](size_t bytes) -> void* {
    void* p = ws + off;
    off += (bytes + 255) & ~(size_t)255;
    return p;
  };
  const size_t HBYTES = (size_t)N_NODES * 128 * sizeof(unsigned short);  // 25.6MB
  const size_t FBYTES = (size_t)N_NODES * 128;                           // 12.8MB
  unsigned short* h0  = (unsigned short*)alloc(HBYTES);
  unsigned short* h1  = (unsigned short*)alloc(HBYTES);
  unsigned char* h0f8 = (unsigned char*)alloc(FBYTES);
  unsigned char* h1f8 = (unsigned char*)alloc(FBYTES);
  unsigned short* WT  = (unsigned short*)alloc(4 * 16384 * sizeof(unsigned short));
  unsigned* bdata2    = (unsigned*)alloc((size_t)NBLK * BREG * 4);  // 6.4MB dense
  int* gcnt           = (int*)alloc((size_t)NBLK * NB * 4);         // 800KB
  int* goff           = (int*)alloc((size_t)NBLK * NB * 4);         // 800KB
  int* col            = (int*)alloc((size_t)NB * CAP * 4);          // 12.8MB
  int* rstart         = (int*)alloc((size_t)N_NODES * 4);
  int* rdeg           = (int*)alloc((size_t)N_NODES * 4);
  (void)ws_size; (void)n_in; (void)out_size;

  // ---- fused LDS-binned bucket scatter + embed ----
  k_bktembed<<<NBLK + EBLK, 512, 0, stream>>>(src, dst, gcnt, goff, bdata2, E,
                                              x, uid, lid, timef, utab, ltab,
                                              Wt, bt, h0, h0f8);
  // ---- CSR finalize + wprep tail ----
  k_bfill<<<NB + WPB, 512, 0, stream>>>(gcnt, goff, bdata2, rstart, rdeg, col,
                                        W1l, W1r, W2l, W2r, WT);

  // ---- layer 1: fused gather-mean + dual GEMM ----
  k_aggemm<false><<<(N_NODES + 63) / 64, 256, 0, stream>>>(
      h0f8, rstart, rdeg, col, h0, WT, WT + 16384, b1, h1, h1f8,
      nullptr, nullptr, nullptr);

  // ---- layer 2: fused gather-mean + dual GEMM + classifier ----
  k_aggemm<true><<<(N_NODES + 63) / 64, 256, 0, stream>>>(
      h1f8, rstart, rdeg, col, h1, WT + 32768, WT + 49152, b2,
      nullptr, nullptr, Wc, bc, out);
}